// Round 1
// baseline (1057.118 us; speedup 1.0000x reference)
//
#include <hip/hip_runtime.h>
#include <hip/hip_bf16.h>

#define N_NODES 50000
#define N_EDGES 500000
#define N_GRAPHS 1000
#define HID 128
#define OUT_F 10
#define NLAYER 4
#define ATOM_F 9
#define ATOM_V 120
#define BOND_F 3
#define BOND_V 6
#define BN_EPS 1e-5f

typedef float float4v __attribute__((ext_vector_type(4)));

// ---------------------------------------------------------------- encoders
__global__ void k_atom_encode(const int* __restrict__ x,
                              const float* __restrict__ atom_emb,
                              float* __restrict__ h) {
    int n = blockIdx.x;
    int f = threadIdx.x;
    float acc = 0.f;
#pragma unroll
    for (int c = 0; c < ATOM_F; ++c) {
        int v = x[n * ATOM_F + c];                 // uniform per block -> scalar load
        acc += atom_emb[(c * ATOM_V + v) * HID + f];
    }
    h[n * HID + f] = acc;
}

// ---------------------------------------------------------------- CSR build
__global__ void k_count(const int* __restrict__ dst, int* __restrict__ cnt) {
    for (int e = blockIdx.x * blockDim.x + threadIdx.x; e < N_EDGES;
         e += gridDim.x * blockDim.x)
        atomicAdd(&cnt[dst[e]], 1);
}

// exclusive scan of cnt[N_NODES]; writes row_ptr[0..N] and rewrites cnt to the
// exclusive offsets (used as the scatter cursor).
__global__ void k_scan(int* __restrict__ cnt, int* __restrict__ row_ptr) {
    __shared__ int sh[1024];
    int carry = 0;
    for (int base = 0; base < N_NODES; base += 1024) {
        int i = base + threadIdx.x;
        int v = (i < N_NODES) ? cnt[i] : 0;
        sh[threadIdx.x] = v;
        __syncthreads();
        for (int ofs = 1; ofs < 1024; ofs <<= 1) {
            int t = (threadIdx.x >= ofs) ? sh[threadIdx.x - ofs] : 0;
            __syncthreads();
            sh[threadIdx.x] += t;
            __syncthreads();
        }
        int incl = sh[threadIdx.x];
        if (i < N_NODES) {
            int excl = carry + incl - v;
            row_ptr[i] = excl;
            cnt[i] = excl;
        }
        int tot = sh[1023];
        __syncthreads();
        carry += tot;
    }
    if (threadIdx.x == 0) row_ptr[N_NODES] = carry;
}

__global__ void k_scatter(const int* __restrict__ src, const int* __restrict__ dst,
                          const int* __restrict__ attr, int* __restrict__ cursor,
                          int* __restrict__ perm_src, int* __restrict__ perm_attr) {
    for (int e = blockIdx.x * blockDim.x + threadIdx.x; e < N_EDGES;
         e += gridDim.x * blockDim.x) {
        int d = dst[e];
        int pos = atomicAdd(&cursor[d], 1);
        perm_src[pos] = src[e];
        int a0 = attr[e * 3 + 0], a1 = attr[e * 3 + 1], a2 = attr[e * 3 + 2];
        perm_attr[pos] = a0 | (a1 << 8) | (a2 << 16);
    }
}

// ---------------------------------------------------------------- aggregate
// z[n] = h[n] + sum_{edges e: dst==n} relu(h[src(e)] + bond_e(e))
__global__ void k_aggregate(const float* __restrict__ h,
                            const int* __restrict__ row_ptr,
                            const int* __restrict__ perm_src,
                            const int* __restrict__ perm_attr,
                            const float* __restrict__ bond_emb,
                            float* __restrict__ z) {
    __shared__ float be[BOND_F * BOND_V * HID];    // 9 KB
    for (int i = threadIdx.x; i < BOND_F * BOND_V * HID; i += blockDim.x)
        be[i] = bond_emb[i];
    __syncthreads();
    int n = blockIdx.x;
    int f = threadIdx.x;
    int s0 = row_ptr[n], s1 = row_ptr[n + 1];
    float acc = h[n * HID + f];
    for (int idx = s0; idx < s1; ++idx) {
        int s = perm_src[idx];
        int a = perm_attr[idx];
        float e = be[(a & 0xff) * HID + f]
                + be[(BOND_V + ((a >> 8) & 0xff)) * HID + f]
                + be[(2 * BOND_V + ((a >> 16) & 0xff)) * HID + f];
        acc += fmaxf(h[s * HID + f] + e, 0.f);
    }
    z[n * HID + f] = acc;
}

// ---------------------------------------------------------------- GEMMs
// 32 rows x 128 cols per block, 256 threads, W in LDS (64KB) + z tile (16KB).
__global__ __launch_bounds__(256) void k_gemm1(const float* __restrict__ zin,
                                               const float* __restrict__ W,
                                               const float* __restrict__ bias,
                                               float* __restrict__ zout) {
    __shared__ float sW[HID * HID];
    __shared__ float sZ[32][HID];
    int tid = threadIdx.x;
    const float4v* W4 = (const float4v*)W;
    float4v* sW4 = (float4v*)sW;
    for (int i = tid; i < HID * HID / 4; i += 256) sW4[i] = W4[i];
    int row0 = blockIdx.x * 32;
    for (int i = tid; i < 32 * HID / 4; i += 256) {
        int r = i / (HID / 4), c4 = i % (HID / 4);
        int gr = row0 + r;
        float4v v = {0.f, 0.f, 0.f, 0.f};
        if (gr < N_NODES) v = ((const float4v*)(zin + gr * HID))[c4];
        ((float4v*)sZ)[i] = v;
    }
    __syncthreads();
    int cg = tid & 31, rg = tid >> 5;
    int c0 = cg * 4, r0 = rg * 4;
    float acc[4][4] = {};
#pragma unroll 4
    for (int k = 0; k < HID; k += 4) {
        float4v w0 = *(const float4v*)(sW + (k + 0) * HID + c0);
        float4v w1 = *(const float4v*)(sW + (k + 1) * HID + c0);
        float4v w2 = *(const float4v*)(sW + (k + 2) * HID + c0);
        float4v w3 = *(const float4v*)(sW + (k + 3) * HID + c0);
#pragma unroll
        for (int r = 0; r < 4; ++r) {
            float4v zv = *(const float4v*)(&sZ[r0 + r][k]);
#pragma unroll
            for (int c = 0; c < 4; ++c) {
                acc[r][c] = fmaf(zv[0], w0[c], acc[r][c]);
                acc[r][c] = fmaf(zv[1], w1[c], acc[r][c]);
                acc[r][c] = fmaf(zv[2], w2[c], acc[r][c]);
                acc[r][c] = fmaf(zv[3], w3[c], acc[r][c]);
            }
        }
    }
    float4v bv = *(const float4v*)(bias + c0);
#pragma unroll
    for (int r = 0; r < 4; ++r) {
        int gr = row0 + r0 + r;
        if (gr < N_NODES) {
            float4v o;
#pragma unroll
            for (int c = 0; c < 4; ++c) o[c] = fmaxf(acc[r][c] + bv[c], 0.f);
            *(float4v*)(zout + gr * HID + c0) = o;
        }
    }
}

// second GEMM + bias + BN(eval) + ReLU + residual, writes h in place
__global__ __launch_bounds__(256) void k_gemm2(const float* __restrict__ zin,
                                               const float* __restrict__ W,
                                               const float* __restrict__ bias,
                                               const float* __restrict__ gamma,
                                               const float* __restrict__ beta,
                                               const float* __restrict__ mean,
                                               const float* __restrict__ var,
                                               float* __restrict__ h) {
    __shared__ float sW[HID * HID];
    __shared__ float sZ[32][HID];
    int tid = threadIdx.x;
    const float4v* W4 = (const float4v*)W;
    float4v* sW4 = (float4v*)sW;
    for (int i = tid; i < HID * HID / 4; i += 256) sW4[i] = W4[i];
    int row0 = blockIdx.x * 32;
    for (int i = tid; i < 32 * HID / 4; i += 256) {
        int r = i / (HID / 4), c4 = i % (HID / 4);
        int gr = row0 + r;
        float4v v = {0.f, 0.f, 0.f, 0.f};
        if (gr < N_NODES) v = ((const float4v*)(zin + gr * HID))[c4];
        ((float4v*)sZ)[i] = v;
    }
    __syncthreads();
    int cg = tid & 31, rg = tid >> 5;
    int c0 = cg * 4, r0 = rg * 4;
    float acc[4][4] = {};
#pragma unroll 4
    for (int k = 0; k < HID; k += 4) {
        float4v w0 = *(const float4v*)(sW + (k + 0) * HID + c0);
        float4v w1 = *(const float4v*)(sW + (k + 1) * HID + c0);
        float4v w2 = *(const float4v*)(sW + (k + 2) * HID + c0);
        float4v w3 = *(const float4v*)(sW + (k + 3) * HID + c0);
#pragma unroll
        for (int r = 0; r < 4; ++r) {
            float4v zv = *(const float4v*)(&sZ[r0 + r][k]);
#pragma unroll
            for (int c = 0; c < 4; ++c) {
                acc[r][c] = fmaf(zv[0], w0[c], acc[r][c]);
                acc[r][c] = fmaf(zv[1], w1[c], acc[r][c]);
                acc[r][c] = fmaf(zv[2], w2[c], acc[r][c]);
                acc[r][c] = fmaf(zv[3], w3[c], acc[r][c]);
            }
        }
    }
    float4v bv = *(const float4v*)(bias + c0);
    float4v gm = *(const float4v*)(gamma + c0);
    float4v bt = *(const float4v*)(beta + c0);
    float4v mn = *(const float4v*)(mean + c0);
    float4v vr = *(const float4v*)(var + c0);
    float4v sc, sf;
#pragma unroll
    for (int c = 0; c < 4; ++c) {
        sc[c] = gm[c] / sqrtf(vr[c] + BN_EPS);
        sf[c] = bt[c] - mn[c] * sc[c];
    }
#pragma unroll
    for (int r = 0; r < 4; ++r) {
        int gr = row0 + r0 + r;
        if (gr < N_NODES) {
            float4v res = *(const float4v*)(h + gr * HID + c0);
            float4v o;
#pragma unroll
            for (int c = 0; c < 4; ++c) {
                float v = (acc[r][c] + bv[c]) * sc[c] + sf[c];
                o[c] = res[c] + fmaxf(v, 0.f);
            }
            *(float4v*)(h + gr * HID + c0) = o;
        }
    }
}

// ---------------------------------------------------------------- pool + MLP
__device__ __forceinline__ int lower_bound(const int* __restrict__ arr, int n, int val) {
    int lo = 0, hi = n;
    while (lo < hi) {
        int mid = (lo + hi) >> 1;
        if (arr[mid] < val) lo = mid + 1; else hi = mid;
    }
    return lo;
}

__global__ void k_pool_mlp(const int* __restrict__ batch, const float* __restrict__ h,
                           const float* __restrict__ mlp_w, const float* __restrict__ mlp_b,
                           float* __restrict__ out) {
    __shared__ float sp[HID];
    int g = blockIdx.x;
    int f = threadIdx.x;
    int start = lower_bound(batch, N_NODES, g);
    int end = lower_bound(batch, N_NODES, g + 1);
    float s = 0.f;
    for (int n = start; n < end; ++n) s += h[n * HID + f];
    float cnt = (float)(end - start);
    sp[f] = s / fmaxf(cnt, 1.0f);
    __syncthreads();
    if (f < OUT_F) {
        float o = mlp_b[f];
        for (int k = 0; k < HID; ++k) o = fmaf(sp[k], mlp_w[k * OUT_F + f], o);
        out[g * OUT_F + f] = o;
    }
}

// ---------------------------------------------------------------- launch
extern "C" void kernel_launch(void* const* d_in, const int* in_sizes, int n_in,
                              void* d_out, int out_size, void* d_ws, size_t ws_size,
                              hipStream_t stream) {
    const int*   x         = (const int*)d_in[0];
    const int*   edge_index= (const int*)d_in[1];
    const int*   edge_attr = (const int*)d_in[2];
    const int*   batch     = (const int*)d_in[3];
    const float* atom_emb  = (const float*)d_in[4];
    const float* bond_emb  = (const float*)d_in[5];
    const float* lin1_w    = (const float*)d_in[6];
    const float* lin1_b    = (const float*)d_in[7];
    const float* lin2_w    = (const float*)d_in[8];
    const float* lin2_b    = (const float*)d_in[9];
    const float* bn_gamma  = (const float*)d_in[10];
    const float* bn_beta   = (const float*)d_in[11];
    const float* bn_mean   = (const float*)d_in[12];
    const float* bn_var    = (const float*)d_in[13];
    const float* mlp_w     = (const float*)d_in[14];
    const float* mlp_b     = (const float*)d_in[15];
    float* out = (float*)d_out;

    // workspace layout (~56 MB)
    char* w = (char*)d_ws;
    float* h = (float*)w;        w += (size_t)N_NODES * HID * 4;
    float* z = (float*)w;        w += (size_t)N_NODES * HID * 4;
    int* row_ptr = (int*)w;      w += (size_t)(N_NODES + 1) * 4;
    int* cursor = (int*)w;       w += (size_t)(N_NODES + 1) * 4;
    int* perm_src = (int*)w;     w += (size_t)N_EDGES * 4;
    int* perm_attr = (int*)w;    w += (size_t)N_EDGES * 4;

    const int* esrc = edge_index;
    const int* edst = edge_index + N_EDGES;

    hipMemsetAsync(cursor, 0, (size_t)N_NODES * 4, stream);
    k_atom_encode<<<N_NODES, HID, 0, stream>>>(x, atom_emb, h);
    k_count<<<2048, 256, 0, stream>>>(edst, cursor);
    k_scan<<<1, 1024, 0, stream>>>(cursor, row_ptr);
    k_scatter<<<2048, 256, 0, stream>>>(esrc, edst, edge_attr, cursor, perm_src, perm_attr);

    int gemm_grid = (N_NODES + 31) / 32;
    for (int i = 0; i < NLAYER; ++i) {
        k_aggregate<<<N_NODES, HID, 0, stream>>>(h, row_ptr, perm_src, perm_attr,
                                                 bond_emb, z);
        k_gemm1<<<gemm_grid, 256, 0, stream>>>(z, lin1_w + (size_t)i * HID * HID,
                                               lin1_b + (size_t)i * HID, z);
        k_gemm2<<<gemm_grid, 256, 0, stream>>>(z, lin2_w + (size_t)i * HID * HID,
                                               lin2_b + (size_t)i * HID,
                                               bn_gamma + (size_t)i * HID,
                                               bn_beta + (size_t)i * HID,
                                               bn_mean + (size_t)i * HID,
                                               bn_var + (size_t)i * HID, h);
    }
    k_pool_mlp<<<N_GRAPHS, HID, 0, stream>>>(batch, h, mlp_w, mlp_b, out);
}

// Round 7
// 770.567 us; speedup vs baseline: 1.3719x; 1.3719x over previous
//
#include <hip/hip_runtime.h>
#include <hip/hip_bf16.h>

#define N_NODES 50000
#define N_EDGES 500000
#define N_GRAPHS 1000
#define HID 128
#define OUT_F 10
#define NLAYER 4
#define ATOM_F 9
#define ATOM_V 120
#define BOND_F 3
#define BOND_V 6
#define BN_EPS 1e-5f

typedef float float4v __attribute__((ext_vector_type(4)));
typedef float float2v __attribute__((ext_vector_type(2)));

// ---------------------------------------------------------------- encoders
// wave-per-node: 64 lanes x float2 cover the 128-float row. (unchanged gen-1)
__global__ __launch_bounds__(256) void k_atom_encode(const int* __restrict__ x,
                                                     const float* __restrict__ atom_emb,
                                                     float* __restrict__ h) {
    int tid = threadIdx.x;
    int wave = tid >> 6, lane = tid & 63;
    int n = blockIdx.x * 4 + wave;
    const float2v* ae2 = (const float2v*)atom_emb;
    float2v acc = {0.f, 0.f};
#pragma unroll
    for (int c = 0; c < ATOM_F; ++c) {
        int v = __builtin_amdgcn_readfirstlane(x[n * ATOM_F + c]);
        acc += ae2[(size_t)(c * ATOM_V + v) * 64 + lane];
    }
    ((float2v*)h)[(size_t)n * 64 + lane] = acc;
}

// ---------------------------------------------------------------- CSR build (unchanged)
__global__ void k_count(const int* __restrict__ dst, int* __restrict__ cnt) {
    for (int e = blockIdx.x * blockDim.x + threadIdx.x; e < N_EDGES;
         e += gridDim.x * blockDim.x)
        atomicAdd(&cnt[dst[e]], 1);
}

__global__ void k_scan(int* __restrict__ cnt, int* __restrict__ row_ptr) {
    __shared__ int sh[1024];
    int carry = 0;
    for (int base = 0; base < N_NODES; base += 1024) {
        int i = base + threadIdx.x;
        int v = (i < N_NODES) ? cnt[i] : 0;
        sh[threadIdx.x] = v;
        __syncthreads();
        for (int ofs = 1; ofs < 1024; ofs <<= 1) {
            int t = (threadIdx.x >= ofs) ? sh[threadIdx.x - ofs] : 0;
            __syncthreads();
            sh[threadIdx.x] += t;
            __syncthreads();
        }
        int incl = sh[threadIdx.x];
        if (i < N_NODES) {
            int excl = carry + incl - v;
            row_ptr[i] = excl;
            cnt[i] = excl;
        }
        int tot = sh[1023];
        __syncthreads();
        carry += tot;
    }
    if (threadIdx.x == 0) row_ptr[N_NODES] = carry;
}

__global__ void k_scatter(const int* __restrict__ src, const int* __restrict__ dst,
                          const int* __restrict__ attr, int* __restrict__ cursor,
                          int2* __restrict__ perm) {
    for (int e = blockIdx.x * blockDim.x + threadIdx.x; e < N_EDGES;
         e += gridDim.x * blockDim.x) {
        int d = dst[e];
        int pos = atomicAdd(&cursor[d], 1);
        int a0 = attr[e * 3 + 0], a1 = attr[e * 3 + 1], a2 = attr[e * 3 + 2];
        int2 p;
        p.x = src[e];
        p.y = a0 | (a1 << 8) | (a2 << 16);
        perm[pos] = p;
    }
}

// ---------------------------------------------------------------- aggregate (unchanged gen-1)
__global__ __launch_bounds__(256) void k_aggregate(const float* __restrict__ h,
                                                   const int* __restrict__ row_ptr,
                                                   const int2* __restrict__ perm,
                                                   const float* __restrict__ bond_emb,
                                                   float* __restrict__ z) {
    __shared__ float be[BOND_F * BOND_V * HID];    // 9 KB
    int tid = threadIdx.x;
    for (int i = tid; i < BOND_F * BOND_V * HID / 2; i += 256)
        ((float2v*)be)[i] = ((const float2v*)bond_emb)[i];
    __syncthreads();

    int wave = tid >> 6, lane = tid & 63;
    int n = blockIdx.x * 4 + wave;
    const float2v* h2 = (const float2v*)h;
    const float2v* be2 = (const float2v*)be;

    int s0 = __builtin_amdgcn_readfirstlane(row_ptr[n]);
    int s1 = __builtin_amdgcn_readfirstlane(row_ptr[n + 1]);

    float2v acc = h2[(size_t)n * 64 + lane];
    int idx = s0;
    for (; idx + 4 <= s1; idx += 4) {
        int2 pA = perm[idx + 0];
        int2 pB = perm[idx + 1];
        int2 pC = perm[idx + 2];
        int2 pD = perm[idx + 3];
        float2v vA = h2[(size_t)pA.x * 64 + lane];
        float2v vB = h2[(size_t)pB.x * 64 + lane];
        float2v vC = h2[(size_t)pC.x * 64 + lane];
        float2v vD = h2[(size_t)pD.x * 64 + lane];
        float2v eA = be2[(pA.y & 0xff) * 64 + lane]
                   + be2[(BOND_V + ((pA.y >> 8) & 0xff)) * 64 + lane]
                   + be2[(2 * BOND_V + ((pA.y >> 16) & 0xff)) * 64 + lane];
        float2v eB = be2[(pB.y & 0xff) * 64 + lane]
                   + be2[(BOND_V + ((pB.y >> 8) & 0xff)) * 64 + lane]
                   + be2[(2 * BOND_V + ((pB.y >> 16) & 0xff)) * 64 + lane];
        float2v eC = be2[(pC.y & 0xff) * 64 + lane]
                   + be2[(BOND_V + ((pC.y >> 8) & 0xff)) * 64 + lane]
                   + be2[(2 * BOND_V + ((pC.y >> 16) & 0xff)) * 64 + lane];
        float2v eD = be2[(pD.y & 0xff) * 64 + lane]
                   + be2[(BOND_V + ((pD.y >> 8) & 0xff)) * 64 + lane]
                   + be2[(2 * BOND_V + ((pD.y >> 16) & 0xff)) * 64 + lane];
        float2v mA = vA + eA; float2v mB = vB + eB;
        float2v mC = vC + eC; float2v mD = vD + eD;
        acc[0] += fmaxf(mA[0], 0.f) + fmaxf(mB[0], 0.f) + fmaxf(mC[0], 0.f) + fmaxf(mD[0], 0.f);
        acc[1] += fmaxf(mA[1], 0.f) + fmaxf(mB[1], 0.f) + fmaxf(mC[1], 0.f) + fmaxf(mD[1], 0.f);
    }
    for (; idx < s1; ++idx) {
        int2 p = perm[idx];
        float2v v = h2[(size_t)p.x * 64 + lane];
        float2v e = be2[(p.y & 0xff) * 64 + lane]
                  + be2[(BOND_V + ((p.y >> 8) & 0xff)) * 64 + lane]
                  + be2[(2 * BOND_V + ((p.y >> 16) & 0xff)) * 64 + lane];
        float2v m = v + e;
        acc[0] += fmaxf(m[0], 0.f);
        acc[1] += fmaxf(m[1], 0.f);
    }
    ((float2v*)z)[(size_t)n * 64 + lane] = acc;
}

// ---------------------------------------------------------------- fused MLP
// One kernel does: t = relu(z@W1+b1); y = t@W2+b2; h = h + relu(BN(y)).
// 64 rows x 128 cols per block, 128 threads, 8x8 per-thread tile.
// The activation tile lives transposed in sT[k][row]; after GEMM1 the t tile
// is written back into sT (barrier-ordered) and feeds GEMM2 from LDS.
#define GR 64
#define KC 32

__global__ __launch_bounds__(128) void k_mlp_fused(const float* __restrict__ zin,
                                                   const float* __restrict__ W1,
                                                   const float* __restrict__ b1,
                                                   const float* __restrict__ W2,
                                                   const float* __restrict__ b2,
                                                   const float* __restrict__ gamma,
                                                   const float* __restrict__ beta,
                                                   const float* __restrict__ mean,
                                                   const float* __restrict__ var,
                                                   float* __restrict__ h) {
    __shared__ float sT[HID][GR + 4];   // 128 x 68 floats = 34.8 KB (transposed acts)
    __shared__ float sW[KC][HID];       // 16 KB weight chunk
    int tid = threadIdx.x;
    int row0 = blockIdx.x * GR;
    int cg = tid & 15, rg = tid >> 4;
    int r0 = rg * 8, c0 = cg * 8;

    // ---- stage z tile transposed (full K=128)
#pragma unroll
    for (int it = 0; it < 16; ++it) {
        int i = it * 128 + tid;          // 0..2047 float4s
        int r = i >> 5, c4 = (i & 31) * 4;
        int gr = row0 + r;
        float4v v = {0.f, 0.f, 0.f, 0.f};
        if (gr < N_NODES) v = *(const float4v*)(zin + (size_t)gr * HID + c4);
        sT[c4 + 0][r] = v[0];
        sT[c4 + 1][r] = v[1];
        sT[c4 + 2][r] = v[2];
        sT[c4 + 3][r] = v[3];
    }

    float acc[8][8] = {};
    // ---- GEMM1: acc = z @ W1
    for (int kc = 0; kc < HID; kc += KC) {
#pragma unroll
        for (int it = 0; it < 8; ++it) {
            int i = it * 128 + tid;      // 0..1023 float4s
            int kk = i >> 5, c4 = (i & 31) * 4;
            *(float4v*)&sW[kk][c4] = *(const float4v*)(W1 + (size_t)(kc + kk) * HID + c4);
        }
        __syncthreads();                 // sT+sW staged (1st iter) / sW re-staged
#pragma unroll 4
        for (int k = 0; k < KC; ++k) {
            float4v a0 = *(const float4v*)&sT[kc + k][r0];
            float4v a1 = *(const float4v*)&sT[kc + k][r0 + 4];
            float4v b0 = *(const float4v*)&sW[k][c0];
            float4v b1v = *(const float4v*)&sW[k][c0 + 4];
            float ar[8] = {a0[0], a0[1], a0[2], a0[3], a1[0], a1[1], a1[2], a1[3]};
            float bc[8] = {b0[0], b0[1], b0[2], b0[3], b1v[0], b1v[1], b1v[2], b1v[3]};
#pragma unroll
            for (int r = 0; r < 8; ++r)
#pragma unroll
                for (int c = 0; c < 8; ++c)
                    acc[r][c] = fmaf(ar[r], bc[c], acc[r][c]);
        }
        __syncthreads();                 // all FMA reads done before next overwrite
    }

    // ---- t = relu(acc + b1), write transposed into sT (reads all done per sync above)
    {
        float4v bv0 = *(const float4v*)(b1 + c0);
        float4v bv1 = *(const float4v*)(b1 + c0 + 4);
        float bb[8] = {bv0[0], bv0[1], bv0[2], bv0[3], bv1[0], bv1[1], bv1[2], bv1[3]};
#pragma unroll
        for (int r = 0; r < 8; ++r)
#pragma unroll
            for (int c = 0; c < 8; ++c) {
                sT[c0 + c][r0 + r] = fmaxf(acc[r][c] + bb[c], 0.f);
                acc[r][c] = 0.f;
            }
    }
    // (t-writes are ordered before GEMM2's FMA reads by the sync inside chunk 0)

    // ---- GEMM2: acc = t @ W2
    for (int kc = 0; kc < HID; kc += KC) {
#pragma unroll
        for (int it = 0; it < 8; ++it) {
            int i = it * 128 + tid;
            int kk = i >> 5, c4 = (i & 31) * 4;
            *(float4v*)&sW[kk][c4] = *(const float4v*)(W2 + (size_t)(kc + kk) * HID + c4);
        }
        __syncthreads();
#pragma unroll 4
        for (int k = 0; k < KC; ++k) {
            float4v a0 = *(const float4v*)&sT[kc + k][r0];
            float4v a1 = *(const float4v*)&sT[kc + k][r0 + 4];
            float4v b0 = *(const float4v*)&sW[k][c0];
            float4v b1v = *(const float4v*)&sW[k][c0 + 4];
            float ar[8] = {a0[0], a0[1], a0[2], a0[3], a1[0], a1[1], a1[2], a1[3]};
            float bc[8] = {b0[0], b0[1], b0[2], b0[3], b1v[0], b1v[1], b1v[2], b1v[3]};
#pragma unroll
            for (int r = 0; r < 8; ++r)
#pragma unroll
                for (int c = 0; c < 8; ++c)
                    acc[r][c] = fmaf(ar[r], bc[c], acc[r][c]);
        }
        __syncthreads();
    }

    // ---- epilogue: bias2 + BN(eval) + ReLU + residual into h
    float sc[8], sf[8];
#pragma unroll
    for (int half = 0; half < 2; ++half) {
        int cb = c0 + half * 4;
        float4v bv = *(const float4v*)(b2 + cb);
        float4v gm = *(const float4v*)(gamma + cb);
        float4v bt = *(const float4v*)(beta + cb);
        float4v mn = *(const float4v*)(mean + cb);
        float4v vr = *(const float4v*)(var + cb);
#pragma unroll
        for (int c = 0; c < 4; ++c) {
            float s = gm[c] / sqrtf(vr[c] + BN_EPS);
            sc[half * 4 + c] = s;
            sf[half * 4 + c] = bt[c] - mn[c] * s + bv[c] * s;
        }
    }
#pragma unroll
    for (int r = 0; r < 8; ++r) {
        int gr = row0 + r0 + r;
        if (gr < N_NODES) {
            float4v res0 = *(const float4v*)(h + (size_t)gr * HID + c0);
            float4v res1 = *(const float4v*)(h + (size_t)gr * HID + c0 + 4);
            float4v o0, o1;
#pragma unroll
            for (int c = 0; c < 4; ++c) {
                float v0 = acc[r][c] * sc[c] + sf[c];
                float v1 = acc[r][c + 4] * sc[c + 4] + sf[c + 4];
                o0[c] = res0[c] + fmaxf(v0, 0.f);
                o1[c] = res1[c] + fmaxf(v1, 0.f);
            }
            *(float4v*)(h + (size_t)gr * HID + c0) = o0;
            *(float4v*)(h + (size_t)gr * HID + c0 + 4) = o1;
        }
    }
}

// ---------------------------------------------------------------- pool + MLP (unchanged)
__device__ __forceinline__ int lower_bound(const int* __restrict__ arr, int n, int val) {
    int lo = 0, hi = n;
    while (lo < hi) {
        int mid = (lo + hi) >> 1;
        if (arr[mid] < val) lo = mid + 1; else hi = mid;
    }
    return lo;
}

__global__ void k_pool_mlp(const int* __restrict__ batch, const float* __restrict__ h,
                           const float* __restrict__ mlp_w, const float* __restrict__ mlp_b,
                           float* __restrict__ out) {
    __shared__ float sp[HID];
    int g = blockIdx.x;
    int f = threadIdx.x;
    int start = lower_bound(batch, N_NODES, g);
    int end = lower_bound(batch, N_NODES, g + 1);
    float s = 0.f;
    for (int n = start; n < end; ++n) s += h[(size_t)n * HID + f];
    float cnt = (float)(end - start);
    sp[f] = s / fmaxf(cnt, 1.0f);
    __syncthreads();
    if (f < OUT_F) {
        float o = mlp_b[f];
        for (int k = 0; k < HID; ++k) o = fmaf(sp[k], mlp_w[k * OUT_F + f], o);
        out[g * OUT_F + f] = o;
    }
}

// ---------------------------------------------------------------- launch
extern "C" void kernel_launch(void* const* d_in, const int* in_sizes, int n_in,
                              void* d_out, int out_size, void* d_ws, size_t ws_size,
                              hipStream_t stream) {
    const int*   x         = (const int*)d_in[0];
    const int*   edge_index= (const int*)d_in[1];
    const int*   edge_attr = (const int*)d_in[2];
    const int*   batch     = (const int*)d_in[3];
    const float* atom_emb  = (const float*)d_in[4];
    const float* bond_emb  = (const float*)d_in[5];
    const float* lin1_w    = (const float*)d_in[6];
    const float* lin1_b    = (const float*)d_in[7];
    const float* lin2_w    = (const float*)d_in[8];
    const float* lin2_b    = (const float*)d_in[9];
    const float* bn_gamma  = (const float*)d_in[10];
    const float* bn_beta   = (const float*)d_in[11];
    const float* bn_mean   = (const float*)d_in[12];
    const float* bn_var    = (const float*)d_in[13];
    const float* mlp_w     = (const float*)d_in[14];
    const float* mlp_b     = (const float*)d_in[15];
    float* out = (float*)d_out;

    // workspace layout
    char* w = (char*)d_ws;
    float* h = (float*)w;        w += (size_t)N_NODES * HID * 4;
    float* z = (float*)w;        w += (size_t)N_NODES * HID * 4;
    int* row_ptr = (int*)w;      w += (size_t)(N_NODES + 1) * 4;
    int* cursor = (int*)w;       w += (size_t)(N_NODES + 1) * 4;
    int2* perm = (int2*)w;       w += (size_t)N_EDGES * 8;

    const int* esrc = edge_index;
    const int* edst = edge_index + N_EDGES;

    hipMemsetAsync(cursor, 0, (size_t)N_NODES * 4, stream);
    k_atom_encode<<<N_NODES / 4, 256, 0, stream>>>(x, atom_emb, h);
    k_count<<<2048, 256, 0, stream>>>(edst, cursor);
    k_scan<<<1, 1024, 0, stream>>>(cursor, row_ptr);
    k_scatter<<<2048, 256, 0, stream>>>(esrc, edst, edge_attr, cursor, perm);

    int gemm_grid = (N_NODES + GR - 1) / GR;
    for (int i = 0; i < NLAYER; ++i) {
        k_aggregate<<<N_NODES / 4, 256, 0, stream>>>(h, row_ptr, perm, bond_emb, z);
        k_mlp_fused<<<gemm_grid, 128, 0, stream>>>(z,
                                                   lin1_w + (size_t)i * HID * HID,
                                                   lin1_b + (size_t)i * HID,
                                                   lin2_w + (size_t)i * HID * HID,
                                                   lin2_b + (size_t)i * HID,
                                                   bn_gamma + (size_t)i * HID,
                                                   bn_beta + (size_t)i * HID,
                                                   bn_mean + (size_t)i * HID,
                                                   bn_var + (size_t)i * HID, h);
    }
    k_pool_mlp<<<N_GRAPHS, HID, 0, stream>>>(batch, h, mlp_w, mlp_b, out);
}

// Round 9
// 690.559 us; speedup vs baseline: 1.5308x; 1.1159x over previous
//
#include <hip/hip_runtime.h>
#include <hip/hip_bf16.h>

#define N_NODES 50000
#define N_EDGES 500000
#define N_GRAPHS 1000
#define HID 128
#define OUT_F 10
#define NLAYER 4
#define ATOM_F 9
#define ATOM_V 120
#define BOND_F 3
#define BOND_V 6
#define BN_EPS 1e-5f
#define SCAN_BLOCKS ((N_NODES + 1023) / 1024)   // 49

typedef float float4v __attribute__((ext_vector_type(4)));
typedef float float2v __attribute__((ext_vector_type(2)));

// ---------------------------------------------------------------- encoders
// wave-per-node: 64 lanes x float2 cover the 128-float row. (unchanged gen-1)
__global__ __launch_bounds__(256) void k_atom_encode(const int* __restrict__ x,
                                                     const float* __restrict__ atom_emb,
                                                     float* __restrict__ h) {
    int tid = threadIdx.x;
    int wave = tid >> 6, lane = tid & 63;
    int n = blockIdx.x * 4 + wave;
    const float2v* ae2 = (const float2v*)atom_emb;
    float2v acc = {0.f, 0.f};
#pragma unroll
    for (int c = 0; c < ATOM_F; ++c) {
        int v = __builtin_amdgcn_readfirstlane(x[n * ATOM_F + c]);
        acc += ae2[(size_t)(c * ATOM_V + v) * 64 + lane];
    }
    ((float2v*)h)[(size_t)n * 64 + lane] = acc;
}

// ---------------------------------------------------------------- CSR build
__global__ void k_count(const int* __restrict__ dst, int* __restrict__ cnt) {
    for (int e = blockIdx.x * blockDim.x + threadIdx.x; e < N_EDGES;
         e += gridDim.x * blockDim.x)
        atomicAdd(&cnt[dst[e]], 1);
}

// hierarchical scan, phase 1: per-block exclusive scan of a 1024-chunk + block total
__global__ __launch_bounds__(1024) void k_scan1(const int* __restrict__ cnt,
                                                int* __restrict__ local,
                                                int* __restrict__ blocksum) {
    __shared__ int sh[1024];
    int i = blockIdx.x * 1024 + threadIdx.x;
    int v = (i < N_NODES) ? cnt[i] : 0;
    sh[threadIdx.x] = v;
    __syncthreads();
    for (int ofs = 1; ofs < 1024; ofs <<= 1) {
        int t = (threadIdx.x >= ofs) ? sh[threadIdx.x - ofs] : 0;
        __syncthreads();
        sh[threadIdx.x] += t;
        __syncthreads();
    }
    if (i < N_NODES) local[i] = sh[threadIdx.x] - v;       // exclusive within block
    if (threadIdx.x == 1023) blocksum[blockIdx.x] = sh[1023];
}

// phase 2: one wave scans the 49 block totals (exclusive), writes grand total
__global__ void k_scan2(int* __restrict__ blocksum, int* __restrict__ row_ptr) {
    int lane = threadIdx.x;   // 64 threads
    int orig = (lane < SCAN_BLOCKS) ? blocksum[lane] : 0;
    int v = orig;
    for (int ofs = 1; ofs < 64; ofs <<= 1) {
        int t = __shfl_up(v, ofs);
        if (lane >= ofs) v += t;
    }
    if (lane < SCAN_BLOCKS) blocksum[lane] = v - orig;     // exclusive
    if (lane == 63) row_ptr[N_NODES] = v;                  // grand total = N_EDGES
}

// phase 3: add block offsets; emit row_ptr and scatter cursor
__global__ __launch_bounds__(1024) void k_scan3(const int* __restrict__ local,
                                                const int* __restrict__ blocksum,
                                                int* __restrict__ row_ptr,
                                                int* __restrict__ cursor) {
    int i = blockIdx.x * 1024 + threadIdx.x;
    if (i < N_NODES) {
        int g = local[i] + blocksum[blockIdx.x];
        row_ptr[i] = g;
        cursor[i] = g;
    }
}

__global__ void k_scatter(const int* __restrict__ src, const int* __restrict__ dst,
                          const int* __restrict__ attr, int* __restrict__ cursor,
                          int2* __restrict__ perm) {
    for (int e = blockIdx.x * blockDim.x + threadIdx.x; e < N_EDGES;
         e += gridDim.x * blockDim.x) {
        int d = dst[e];
        int pos = atomicAdd(&cursor[d], 1);
        int a0 = attr[e * 3 + 0], a1 = attr[e * 3 + 1], a2 = attr[e * 3 + 2];
        int2 p;
        p.x = src[e];
        p.y = a0 | (a1 << 8) | (a2 << 16);
        perm[pos] = p;
    }
}

// ---------------------------------------------------------------- aggregate (unchanged gen-1)
__global__ __launch_bounds__(256) void k_aggregate(const float* __restrict__ h,
                                                   const int* __restrict__ row_ptr,
                                                   const int2* __restrict__ perm,
                                                   const float* __restrict__ bond_emb,
                                                   float* __restrict__ z) {
    __shared__ float be[BOND_F * BOND_V * HID];    // 9 KB
    int tid = threadIdx.x;
    for (int i = tid; i < BOND_F * BOND_V * HID / 2; i += 256)
        ((float2v*)be)[i] = ((const float2v*)bond_emb)[i];
    __syncthreads();

    int wave = tid >> 6, lane = tid & 63;
    int n = blockIdx.x * 4 + wave;
    const float2v* h2 = (const float2v*)h;
    const float2v* be2 = (const float2v*)be;

    int s0 = __builtin_amdgcn_readfirstlane(row_ptr[n]);
    int s1 = __builtin_amdgcn_readfirstlane(row_ptr[n + 1]);

    float2v acc = h2[(size_t)n * 64 + lane];
    int idx = s0;
    for (; idx + 4 <= s1; idx += 4) {
        int2 pA = perm[idx + 0];
        int2 pB = perm[idx + 1];
        int2 pC = perm[idx + 2];
        int2 pD = perm[idx + 3];
        float2v vA = h2[(size_t)pA.x * 64 + lane];
        float2v vB = h2[(size_t)pB.x * 64 + lane];
        float2v vC = h2[(size_t)pC.x * 64 + lane];
        float2v vD = h2[(size_t)pD.x * 64 + lane];
        float2v eA = be2[(pA.y & 0xff) * 64 + lane]
                   + be2[(BOND_V + ((pA.y >> 8) & 0xff)) * 64 + lane]
                   + be2[(2 * BOND_V + ((pA.y >> 16) & 0xff)) * 64 + lane];
        float2v eB = be2[(pB.y & 0xff) * 64 + lane]
                   + be2[(BOND_V + ((pB.y >> 8) & 0xff)) * 64 + lane]
                   + be2[(2 * BOND_V + ((pB.y >> 16) & 0xff)) * 64 + lane];
        float2v eC = be2[(pC.y & 0xff) * 64 + lane]
                   + be2[(BOND_V + ((pC.y >> 8) & 0xff)) * 64 + lane]
                   + be2[(2 * BOND_V + ((pC.y >> 16) & 0xff)) * 64 + lane];
        float2v eD = be2[(pD.y & 0xff) * 64 + lane]
                   + be2[(BOND_V + ((pD.y >> 8) & 0xff)) * 64 + lane]
                   + be2[(2 * BOND_V + ((pD.y >> 16) & 0xff)) * 64 + lane];
        float2v mA = vA + eA; float2v mB = vB + eB;
        float2v mC = vC + eC; float2v mD = vD + eD;
        acc[0] += fmaxf(mA[0], 0.f) + fmaxf(mB[0], 0.f) + fmaxf(mC[0], 0.f) + fmaxf(mD[0], 0.f);
        acc[1] += fmaxf(mA[1], 0.f) + fmaxf(mB[1], 0.f) + fmaxf(mC[1], 0.f) + fmaxf(mD[1], 0.f);
    }
    for (; idx < s1; ++idx) {
        int2 p = perm[idx];
        float2v v = h2[(size_t)p.x * 64 + lane];
        float2v e = be2[(p.y & 0xff) * 64 + lane]
                  + be2[(BOND_V + ((p.y >> 8) & 0xff)) * 64 + lane]
                  + be2[(2 * BOND_V + ((p.y >> 16) & 0xff)) * 64 + lane];
        float2v m = v + e;
        acc[0] += fmaxf(m[0], 0.f);
        acc[1] += fmaxf(m[1], 0.f);
    }
    ((float2v*)z)[(size_t)n * 64 + lane] = acc;
}

// ---------------------------------------------------------------- fused MLP (unchanged gen-2)
// t = relu(z@W1+b1); y = t@W2+b2; h = h + relu(BN(y)).
#define GR 64
#define KC 32

__global__ __launch_bounds__(128) void k_mlp_fused(const float* __restrict__ zin,
                                                   const float* __restrict__ W1,
                                                   const float* __restrict__ b1,
                                                   const float* __restrict__ W2,
                                                   const float* __restrict__ b2,
                                                   const float* __restrict__ gamma,
                                                   const float* __restrict__ beta,
                                                   const float* __restrict__ mean,
                                                   const float* __restrict__ var,
                                                   float* __restrict__ h) {
    __shared__ float sT[HID][GR + 4];   // 34.8 KB (transposed acts)
    __shared__ float sW[KC][HID];       // 16 KB weight chunk
    int tid = threadIdx.x;
    int row0 = blockIdx.x * GR;
    int cg = tid & 15, rg = tid >> 4;
    int r0 = rg * 8, c0 = cg * 8;

#pragma unroll
    for (int it = 0; it < 16; ++it) {
        int i = it * 128 + tid;
        int r = i >> 5, c4 = (i & 31) * 4;
        int gr = row0 + r;
        float4v v = {0.f, 0.f, 0.f, 0.f};
        if (gr < N_NODES) v = *(const float4v*)(zin + (size_t)gr * HID + c4);
        sT[c4 + 0][r] = v[0];
        sT[c4 + 1][r] = v[1];
        sT[c4 + 2][r] = v[2];
        sT[c4 + 3][r] = v[3];
    }

    float acc[8][8] = {};
    for (int kc = 0; kc < HID; kc += KC) {
#pragma unroll
        for (int it = 0; it < 8; ++it) {
            int i = it * 128 + tid;
            int kk = i >> 5, c4 = (i & 31) * 4;
            *(float4v*)&sW[kk][c4] = *(const float4v*)(W1 + (size_t)(kc + kk) * HID + c4);
        }
        __syncthreads();
#pragma unroll 4
        for (int k = 0; k < KC; ++k) {
            float4v a0 = *(const float4v*)&sT[kc + k][r0];
            float4v a1 = *(const float4v*)&sT[kc + k][r0 + 4];
            float4v b0 = *(const float4v*)&sW[k][c0];
            float4v b1v = *(const float4v*)&sW[k][c0 + 4];
            float ar[8] = {a0[0], a0[1], a0[2], a0[3], a1[0], a1[1], a1[2], a1[3]};
            float bc[8] = {b0[0], b0[1], b0[2], b0[3], b1v[0], b1v[1], b1v[2], b1v[3]};
#pragma unroll
            for (int r = 0; r < 8; ++r)
#pragma unroll
                for (int c = 0; c < 8; ++c)
                    acc[r][c] = fmaf(ar[r], bc[c], acc[r][c]);
        }
        __syncthreads();
    }

    {
        float4v bv0 = *(const float4v*)(b1 + c0);
        float4v bv1 = *(const float4v*)(b1 + c0 + 4);
        float bb[8] = {bv0[0], bv0[1], bv0[2], bv0[3], bv1[0], bv1[1], bv1[2], bv1[3]};
#pragma unroll
        for (int r = 0; r < 8; ++r)
#pragma unroll
            for (int c = 0; c < 8; ++c) {
                sT[c0 + c][r0 + r] = fmaxf(acc[r][c] + bb[c], 0.f);
                acc[r][c] = 0.f;
            }
    }

    for (int kc = 0; kc < HID; kc += KC) {
#pragma unroll
        for (int it = 0; it < 8; ++it) {
            int i = it * 128 + tid;
            int kk = i >> 5, c4 = (i & 31) * 4;
            *(float4v*)&sW[kk][c4] = *(const float4v*)(W2 + (size_t)(kc + kk) * HID + c4);
        }
        __syncthreads();
#pragma unroll 4
        for (int k = 0; k < KC; ++k) {
            float4v a0 = *(const float4v*)&sT[kc + k][r0];
            float4v a1 = *(const float4v*)&sT[kc + k][r0 + 4];
            float4v b0 = *(const float4v*)&sW[k][c0];
            float4v b1v = *(const float4v*)&sW[k][c0 + 4];
            float ar[8] = {a0[0], a0[1], a0[2], a0[3], a1[0], a1[1], a1[2], a1[3]};
            float bc[8] = {b0[0], b0[1], b0[2], b0[3], b1v[0], b1v[1], b1v[2], b1v[3]};
#pragma unroll
            for (int r = 0; r < 8; ++r)
#pragma unroll
                for (int c = 0; c < 8; ++c)
                    acc[r][c] = fmaf(ar[r], bc[c], acc[r][c]);
        }
        __syncthreads();
    }

    float sc[8], sf[8];
#pragma unroll
    for (int half = 0; half < 2; ++half) {
        int cb = c0 + half * 4;
        float4v bv = *(const float4v*)(b2 + cb);
        float4v gm = *(const float4v*)(gamma + cb);
        float4v bt = *(const float4v*)(beta + cb);
        float4v mn = *(const float4v*)(mean + cb);
        float4v vr = *(const float4v*)(var + cb);
#pragma unroll
        for (int c = 0; c < 4; ++c) {
            float s = gm[c] / sqrtf(vr[c] + BN_EPS);
            sc[half * 4 + c] = s;
            sf[half * 4 + c] = bt[c] - mn[c] * s + bv[c] * s;
        }
    }
#pragma unroll
    for (int r = 0; r < 8; ++r) {
        int gr = row0 + r0 + r;
        if (gr < N_NODES) {
            float4v res0 = *(const float4v*)(h + (size_t)gr * HID + c0);
            float4v res1 = *(const float4v*)(h + (size_t)gr * HID + c0 + 4);
            float4v o0, o1;
#pragma unroll
            for (int c = 0; c < 4; ++c) {
                float v0 = acc[r][c] * sc[c] + sf[c];
                float v1 = acc[r][c + 4] * sc[c + 4] + sf[c + 4];
                o0[c] = res0[c] + fmaxf(v0, 0.f);
                o1[c] = res1[c] + fmaxf(v1, 0.f);
            }
            *(float4v*)(h + (size_t)gr * HID + c0) = o0;
            *(float4v*)(h + (size_t)gr * HID + c0 + 4) = o1;
        }
    }
}

// ---------------------------------------------------------------- pool + MLP (unchanged)
__device__ __forceinline__ int lower_bound(const int* __restrict__ arr, int n, int val) {
    int lo = 0, hi = n;
    while (lo < hi) {
        int mid = (lo + hi) >> 1;
        if (arr[mid] < val) lo = mid + 1; else hi = mid;
    }
    return lo;
}

__global__ void k_pool_mlp(const int* __restrict__ batch, const float* __restrict__ h,
                           const float* __restrict__ mlp_w, const float* __restrict__ mlp_b,
                           float* __restrict__ out) {
    __shared__ float sp[HID];
    int g = blockIdx.x;
    int f = threadIdx.x;
    int start = lower_bound(batch, N_NODES, g);
    int end = lower_bound(batch, N_NODES, g + 1);
    float s = 0.f;
    for (int n = start; n < end; ++n) s += h[(size_t)n * HID + f];
    float cnt = (float)(end - start);
    sp[f] = s / fmaxf(cnt, 1.0f);
    __syncthreads();
    if (f < OUT_F) {
        float o = mlp_b[f];
        for (int k = 0; k < HID; ++k) o = fmaf(sp[k], mlp_w[k * OUT_F + f], o);
        out[g * OUT_F + f] = o;
    }
}

// ---------------------------------------------------------------- launch
extern "C" void kernel_launch(void* const* d_in, const int* in_sizes, int n_in,
                              void* d_out, int out_size, void* d_ws, size_t ws_size,
                              hipStream_t stream) {
    const int*   x         = (const int*)d_in[0];
    const int*   edge_index= (const int*)d_in[1];
    const int*   edge_attr = (const int*)d_in[2];
    const int*   batch     = (const int*)d_in[3];
    const float* atom_emb  = (const float*)d_in[4];
    const float* bond_emb  = (const float*)d_in[5];
    const float* lin1_w    = (const float*)d_in[6];
    const float* lin1_b    = (const float*)d_in[7];
    const float* lin2_w    = (const float*)d_in[8];
    const float* lin2_b    = (const float*)d_in[9];
    const float* bn_gamma  = (const float*)d_in[10];
    const float* bn_beta   = (const float*)d_in[11];
    const float* bn_mean   = (const float*)d_in[12];
    const float* bn_var    = (const float*)d_in[13];
    const float* mlp_w     = (const float*)d_in[14];
    const float* mlp_b     = (const float*)d_in[15];
    float* out = (float*)d_out;

    // workspace layout
    char* w = (char*)d_ws;
    float* h = (float*)w;        w += (size_t)N_NODES * HID * 4;
    float* z = (float*)w;        w += (size_t)N_NODES * HID * 4;
    int* row_ptr = (int*)w;      w += (size_t)(N_NODES + 1) * 4;
    int* cursor = (int*)w;       w += (size_t)(N_NODES + 1) * 4;
    int2* perm = (int2*)w;       w += (size_t)N_EDGES * 8;
    int* blocksum = (int*)w;     w += 64 * 4;
    // scan scratch aliases z: consumed by k_scan3 before the first k_aggregate writes z
    int* local = (int*)z;

    const int* esrc = edge_index;
    const int* edst = edge_index + N_EDGES;

    hipMemsetAsync(cursor, 0, (size_t)N_NODES * 4, stream);
    k_atom_encode<<<N_NODES / 4, 256, 0, stream>>>(x, atom_emb, h);
    k_count<<<2048, 256, 0, stream>>>(edst, cursor);
    k_scan1<<<SCAN_BLOCKS, 1024, 0, stream>>>(cursor, local, blocksum);
    k_scan2<<<1, 64, 0, stream>>>(blocksum, row_ptr);
    k_scan3<<<SCAN_BLOCKS, 1024, 0, stream>>>(local, blocksum, row_ptr, cursor);
    k_scatter<<<2048, 256, 0, stream>>>(esrc, edst, edge_attr, cursor, perm);

    int gemm_grid = (N_NODES + GR - 1) / GR;
    for (int i = 0; i < NLAYER; ++i) {
        k_aggregate<<<N_NODES / 4, 256, 0, stream>>>(h, row_ptr, perm, bond_emb, z);
        k_mlp_fused<<<gemm_grid, 128, 0, stream>>>(z,
                                                   lin1_w + (size_t)i * HID * HID,
                                                   lin1_b + (size_t)i * HID,
                                                   lin2_w + (size_t)i * HID * HID,
                                                   lin2_b + (size_t)i * HID,
                                                   bn_gamma + (size_t)i * HID,
                                                   bn_beta + (size_t)i * HID,
                                                   bn_mean + (size_t)i * HID,
                                                   bn_var + (size_t)i * HID, h);
    }
    k_pool_mlp<<<N_GRAPHS, HID, 0, stream>>>(batch, h, mlp_w, mlp_b, out);
}

// Round 12
// 548.360 us; speedup vs baseline: 1.9278x; 1.2593x over previous
//
#include <hip/hip_runtime.h>
#include <hip/hip_bf16.h>

#define N_NODES 50000
#define N_PAD 50048               // 782*64, pad so MFMA A-loads never go OOB
#define N_EDGES 500000
#define N_GRAPHS 1000
#define HID 128
#define OUT_F 10
#define NLAYER 4
#define ATOM_F 9
#define ATOM_V 120
#define BOND_F 3
#define BOND_V 6
#define BN_EPS 1e-5f
#define SCAN_BLOCKS ((N_NODES + 1023) / 1024)   // 49

typedef float float4v __attribute__((ext_vector_type(4)));
typedef float float2v __attribute__((ext_vector_type(2)));
typedef short bf16x8 __attribute__((ext_vector_type(8)));   // 8 bf16 = 4 VGPRs
typedef float f32x4 __attribute__((ext_vector_type(4)));

__device__ __forceinline__ unsigned short f2bf(float f) {
    __hip_bfloat16 b = __float2bfloat16(f);
    return *reinterpret_cast<unsigned short*>(&b);
}

// ---------------------------------------------------------------- encoders (unchanged)
__global__ __launch_bounds__(256) void k_atom_encode(const int* __restrict__ x,
                                                     const float* __restrict__ atom_emb,
                                                     float* __restrict__ h) {
    int tid = threadIdx.x;
    int wave = tid >> 6, lane = tid & 63;
    int n = blockIdx.x * 4 + wave;
    const float2v* ae2 = (const float2v*)atom_emb;
    float2v acc = {0.f, 0.f};
#pragma unroll
    for (int c = 0; c < ATOM_F; ++c) {
        int v = __builtin_amdgcn_readfirstlane(x[n * ATOM_F + c]);
        acc += ae2[(size_t)(c * ATOM_V + v) * 64 + lane];
    }
    ((float2v*)h)[(size_t)n * 64 + lane] = acc;
}

// ---------------------------------------------------------------- weight convert
// wtb[(l*2+m)][c][k] = bf16( W_m[l][k][c] )   -- transposed so B-fragments are contiguous
__global__ __launch_bounds__(256) void k_convert_w(const float* __restrict__ w1,
                                                   const float* __restrict__ w2,
                                                   unsigned short* __restrict__ wtb) {
    int idx = blockIdx.x * 256 + threadIdx.x;      // 0 .. 131071
    int l = idx >> 15;
    int rem = idx & 32767;
    int m = rem >> 14;
    int rem2 = rem & 16383;
    int c = rem2 >> 7, k = rem2 & 127;
    const float* src = m ? w2 : w1;
    wtb[idx] = f2bf(src[(size_t)l * HID * HID + k * HID + c]);
}

// ---------------------------------------------------------------- CSR build (unchanged gen-3)
__global__ void k_count(const int* __restrict__ dst, int* __restrict__ cnt) {
    for (int e = blockIdx.x * blockDim.x + threadIdx.x; e < N_EDGES;
         e += gridDim.x * blockDim.x)
        atomicAdd(&cnt[dst[e]], 1);
}

__global__ __launch_bounds__(1024) void k_scan1(const int* __restrict__ cnt,
                                                int* __restrict__ local,
                                                int* __restrict__ blocksum) {
    __shared__ int sh[1024];
    int i = blockIdx.x * 1024 + threadIdx.x;
    int v = (i < N_NODES) ? cnt[i] : 0;
    sh[threadIdx.x] = v;
    __syncthreads();
    for (int ofs = 1; ofs < 1024; ofs <<= 1) {
        int t = (threadIdx.x >= ofs) ? sh[threadIdx.x - ofs] : 0;
        __syncthreads();
        sh[threadIdx.x] += t;
        __syncthreads();
    }
    if (i < N_NODES) local[i] = sh[threadIdx.x] - v;
    if (threadIdx.x == 1023) blocksum[blockIdx.x] = sh[1023];
}

__global__ void k_scan2(int* __restrict__ blocksum, int* __restrict__ row_ptr) {
    int lane = threadIdx.x;   // 64 threads
    int orig = (lane < SCAN_BLOCKS) ? blocksum[lane] : 0;
    int v = orig;
    for (int ofs = 1; ofs < 64; ofs <<= 1) {
        int t = __shfl_up(v, ofs);
        if (lane >= ofs) v += t;
    }
    if (lane < SCAN_BLOCKS) blocksum[lane] = v - orig;
    if (lane == 63) row_ptr[N_NODES] = v;
}

__global__ __launch_bounds__(1024) void k_scan3(const int* __restrict__ local,
                                                const int* __restrict__ blocksum,
                                                int* __restrict__ row_ptr,
                                                int* __restrict__ cursor) {
    int i = blockIdx.x * 1024 + threadIdx.x;
    if (i < N_NODES) {
        int g = local[i] + blocksum[blockIdx.x];
        row_ptr[i] = g;
        cursor[i] = g;
    }
}

__global__ void k_scatter(const int* __restrict__ src, const int* __restrict__ dst,
                          const int* __restrict__ attr, int* __restrict__ cursor,
                          int2* __restrict__ perm) {
    for (int e = blockIdx.x * blockDim.x + threadIdx.x; e < N_EDGES;
         e += gridDim.x * blockDim.x) {
        int d = dst[e];
        int pos = atomicAdd(&cursor[d], 1);
        int a0 = attr[e * 3 + 0], a1 = attr[e * 3 + 1], a2 = attr[e * 3 + 2];
        int2 p;
        p.x = src[e];
        p.y = a0 | (a1 << 8) | (a2 << 16);
        perm[pos] = p;
    }
}

// ---------------------------------------------------------------- aggregate
// unchanged gather structure; output z now written as bf16 (one RNE round)
__global__ __launch_bounds__(256) void k_aggregate(const float* __restrict__ h,
                                                   const int* __restrict__ row_ptr,
                                                   const int2* __restrict__ perm,
                                                   const float* __restrict__ bond_emb,
                                                   unsigned int* __restrict__ zb) {
    __shared__ float be[BOND_F * BOND_V * HID];    // 9 KB
    int tid = threadIdx.x;
    for (int i = tid; i < BOND_F * BOND_V * HID / 2; i += 256)
        ((float2v*)be)[i] = ((const float2v*)bond_emb)[i];
    __syncthreads();

    int wave = tid >> 6, lane = tid & 63;
    int n = blockIdx.x * 4 + wave;
    const float2v* h2 = (const float2v*)h;
    const float2v* be2 = (const float2v*)be;

    int s0 = __builtin_amdgcn_readfirstlane(row_ptr[n]);
    int s1 = __builtin_amdgcn_readfirstlane(row_ptr[n + 1]);

    float2v acc = h2[(size_t)n * 64 + lane];
    int idx = s0;
    for (; idx + 4 <= s1; idx += 4) {
        int2 pA = perm[idx + 0];
        int2 pB = perm[idx + 1];
        int2 pC = perm[idx + 2];
        int2 pD = perm[idx + 3];
        float2v vA = h2[(size_t)pA.x * 64 + lane];
        float2v vB = h2[(size_t)pB.x * 64 + lane];
        float2v vC = h2[(size_t)pC.x * 64 + lane];
        float2v vD = h2[(size_t)pD.x * 64 + lane];
        float2v eA = be2[(pA.y & 0xff) * 64 + lane]
                   + be2[(BOND_V + ((pA.y >> 8) & 0xff)) * 64 + lane]
                   + be2[(2 * BOND_V + ((pA.y >> 16) & 0xff)) * 64 + lane];
        float2v eB = be2[(pB.y & 0xff) * 64 + lane]
                   + be2[(BOND_V + ((pB.y >> 8) & 0xff)) * 64 + lane]
                   + be2[(2 * BOND_V + ((pB.y >> 16) & 0xff)) * 64 + lane];
        float2v eC = be2[(pC.y & 0xff) * 64 + lane]
                   + be2[(BOND_V + ((pC.y >> 8) & 0xff)) * 64 + lane]
                   + be2[(2 * BOND_V + ((pC.y >> 16) & 0xff)) * 64 + lane];
        float2v eD = be2[(pD.y & 0xff) * 64 + lane]
                   + be2[(BOND_V + ((pD.y >> 8) & 0xff)) * 64 + lane]
                   + be2[(2 * BOND_V + ((pD.y >> 16) & 0xff)) * 64 + lane];
        float2v mA = vA + eA; float2v mB = vB + eB;
        float2v mC = vC + eC; float2v mD = vD + eD;
        acc[0] += fmaxf(mA[0], 0.f) + fmaxf(mB[0], 0.f) + fmaxf(mC[0], 0.f) + fmaxf(mD[0], 0.f);
        acc[1] += fmaxf(mA[1], 0.f) + fmaxf(mB[1], 0.f) + fmaxf(mC[1], 0.f) + fmaxf(mD[1], 0.f);
    }
    for (; idx < s1; ++idx) {
        int2 p = perm[idx];
        float2v v = h2[(size_t)p.x * 64 + lane];
        float2v e = be2[(p.y & 0xff) * 64 + lane]
                  + be2[(BOND_V + ((p.y >> 8) & 0xff)) * 64 + lane]
                  + be2[(2 * BOND_V + ((p.y >> 16) & 0xff)) * 64 + lane];
        float2v m = v + e;
        acc[0] += fmaxf(m[0], 0.f);
        acc[1] += fmaxf(m[1], 0.f);
    }
    zb[(size_t)n * 64 + lane] =
        (unsigned int)f2bf(acc[0]) | ((unsigned int)f2bf(acc[1]) << 16);
}

// ---------------------------------------------------------------- MFMA fused MLP
// 64 rows x 128 cols per block, 4 waves; mfma_f32_16x16x32_bf16.
// A (z rows, bf16) direct from global; B = transposed bf16 weights (contiguous k).
// t intermediate in 16KB XOR-swizzled LDS. Epilogue fuses bias+BN+ReLU+residual.
#define MROWS 64

__global__ __launch_bounds__(256) void k_mlp_mfma(const unsigned short* __restrict__ zb,
                                                  const unsigned short* __restrict__ w1t,
                                                  const float* __restrict__ b1,
                                                  const unsigned short* __restrict__ w2t,
                                                  const float* __restrict__ b2,
                                                  const float* __restrict__ gamma,
                                                  const float* __restrict__ beta,
                                                  const float* __restrict__ mean,
                                                  const float* __restrict__ var,
                                                  float* __restrict__ h) {
    __shared__ unsigned short tld[MROWS * HID];    // 16 KB, swizzled
    int tid = threadIdx.x;
    int wid = tid >> 6, lane = tid & 63;
    int lrow = lane & 15, kg = lane >> 4;
    int rowBase = blockIdx.x * MROWS + wid * 16;   // this wave's first row

    // ---- GEMM1: acc[ct] = z(16x128) @ W1(128x16ct)
    const bf16x8* zrow = (const bf16x8*)(zb + (size_t)(rowBase + lrow) * HID);
    bf16x8 a0 = zrow[kg];
    bf16x8 a1 = zrow[4 + kg];
    bf16x8 a2 = zrow[8 + kg];
    bf16x8 a3 = zrow[12 + kg];

    f32x4 acc[8];
#pragma unroll
    for (int ct = 0; ct < 8; ++ct) {
        const bf16x8* wcol = (const bf16x8*)(w1t + (size_t)(ct * 16 + lrow) * HID);
        f32x4 c = {0.f, 0.f, 0.f, 0.f};
        c = __builtin_amdgcn_mfma_f32_16x16x32_bf16(a0, wcol[kg], c, 0, 0, 0);
        c = __builtin_amdgcn_mfma_f32_16x16x32_bf16(a1, wcol[4 + kg], c, 0, 0, 0);
        c = __builtin_amdgcn_mfma_f32_16x16x32_bf16(a2, wcol[8 + kg], c, 0, 0, 0);
        c = __builtin_amdgcn_mfma_f32_16x16x32_bf16(a3, wcol[12 + kg], c, 0, 0, 0);
        acc[ct] = c;
    }

    // ---- t = relu(acc + b1) -> swizzled LDS bf16
#pragma unroll
    for (int ct = 0; ct < 8; ++ct) {
        int col = ct * 16 + lrow;
        float bias = b1[col];
#pragma unroll
        for (int i = 0; i < 4; ++i) {
            int trow = wid * 16 + kg * 4 + i;               // C row = (lane>>4)*4+i
            float v = fmaxf(acc[ct][i] + bias, 0.f);
            tld[trow * HID + (col ^ ((trow & 7) << 3))] = f2bf(v);
        }
    }
    __syncthreads();

    // ---- GEMM2: A from LDS t (swizzled b128 reads)
    int arow = wid * 16 + lrow;
    int sw = (arow & 7) << 3;
    bf16x8 t0 = *(const bf16x8*)&tld[arow * HID + ((0 * 32 + kg * 8) ^ sw)];
    bf16x8 t1 = *(const bf16x8*)&tld[arow * HID + ((1 * 32 + kg * 8) ^ sw)];
    bf16x8 t2 = *(const bf16x8*)&tld[arow * HID + ((2 * 32 + kg * 8) ^ sw)];
    bf16x8 t3 = *(const bf16x8*)&tld[arow * HID + ((3 * 32 + kg * 8) ^ sw)];

#pragma unroll
    for (int ct = 0; ct < 8; ++ct) {
        const bf16x8* wcol = (const bf16x8*)(w2t + (size_t)(ct * 16 + lrow) * HID);
        f32x4 c = {0.f, 0.f, 0.f, 0.f};
        c = __builtin_amdgcn_mfma_f32_16x16x32_bf16(t0, wcol[kg], c, 0, 0, 0);
        c = __builtin_amdgcn_mfma_f32_16x16x32_bf16(t1, wcol[4 + kg], c, 0, 0, 0);
        c = __builtin_amdgcn_mfma_f32_16x16x32_bf16(t2, wcol[8 + kg], c, 0, 0, 0);
        c = __builtin_amdgcn_mfma_f32_16x16x32_bf16(t3, wcol[12 + kg], c, 0, 0, 0);
        acc[ct] = c;
    }

    // ---- epilogue: bias2 + BN(eval) + ReLU + residual into h (fp32)
#pragma unroll
    for (int ct = 0; ct < 8; ++ct) {
        int col = ct * 16 + lrow;
        float scl = gamma[col] / sqrtf(var[col] + BN_EPS);
        float sft = (b2[col] - mean[col]) * scl + beta[col];
#pragma unroll
        for (int i = 0; i < 4; ++i) {
            int row = rowBase + kg * 4 + i;
            if (row < N_NODES) {
                float* hp = h + (size_t)row * HID + col;
                float r = *hp;
                *hp = r + fmaxf(acc[ct][i] * scl + sft, 0.f);
            }
        }
    }
}

// ---------------------------------------------------------------- pool + MLP (unchanged)
__device__ __forceinline__ int lower_bound(const int* __restrict__ arr, int n, int val) {
    int lo = 0, hi = n;
    while (lo < hi) {
        int mid = (lo + hi) >> 1;
        if (arr[mid] < val) lo = mid + 1; else hi = mid;
    }
    return lo;
}

__global__ void k_pool_mlp(const int* __restrict__ batch, const float* __restrict__ h,
                           const float* __restrict__ mlp_w, const float* __restrict__ mlp_b,
                           float* __restrict__ out) {
    __shared__ float sp[HID];
    int g = blockIdx.x;
    int f = threadIdx.x;
    int start = lower_bound(batch, N_NODES, g);
    int end = lower_bound(batch, N_NODES, g + 1);
    float s = 0.f;
    for (int n = start; n < end; ++n) s += h[(size_t)n * HID + f];
    float cnt = (float)(end - start);
    sp[f] = s / fmaxf(cnt, 1.0f);
    __syncthreads();
    if (f < OUT_F) {
        float o = mlp_b[f];
        for (int k = 0; k < HID; ++k) o = fmaf(sp[k], mlp_w[k * OUT_F + f], o);
        out[g * OUT_F + f] = o;
    }
}

// ---------------------------------------------------------------- launch
extern "C" void kernel_launch(void* const* d_in, const int* in_sizes, int n_in,
                              void* d_out, int out_size, void* d_ws, size_t ws_size,
                              hipStream_t stream) {
    const int*   x         = (const int*)d_in[0];
    const int*   edge_index= (const int*)d_in[1];
    const int*   edge_attr = (const int*)d_in[2];
    const int*   batch     = (const int*)d_in[3];
    const float* atom_emb  = (const float*)d_in[4];
    const float* bond_emb  = (const float*)d_in[5];
    const float* lin1_w    = (const float*)d_in[6];
    const float* lin1_b    = (const float*)d_in[7];
    const float* lin2_w    = (const float*)d_in[8];
    const float* lin2_b    = (const float*)d_in[9];
    const float* bn_gamma  = (const float*)d_in[10];
    const float* bn_beta   = (const float*)d_in[11];
    const float* bn_mean   = (const float*)d_in[12];
    const float* bn_var    = (const float*)d_in[13];
    const float* mlp_w     = (const float*)d_in[14];
    const float* mlp_b     = (const float*)d_in[15];
    float* out = (float*)d_out;

    // workspace layout (~43 MB)
    char* w = (char*)d_ws;
    float* h = (float*)w;            w += (size_t)N_NODES * HID * 4;
    unsigned int* zb = (unsigned int*)w;  w += (size_t)N_PAD * HID * 2;   // bf16 z
    int* row_ptr = (int*)w;          w += (size_t)(N_NODES + 1) * 4;
    int* cursor = (int*)w;           w += (size_t)(N_NODES + 1) * 4;
    int2* perm = (int2*)w;           w += (size_t)N_EDGES * 8;
    int* blocksum = (int*)w;         w += 64 * 4;
    unsigned short* wtb = (unsigned short*)w; w += (size_t)NLAYER * 2 * HID * HID * 2;
    // scan scratch aliases zb: consumed by k_scan3 before first k_aggregate writes zb
    int* local = (int*)zb;

    const int* esrc = edge_index;
    const int* edst = edge_index + N_EDGES;

    hipMemsetAsync(cursor, 0, (size_t)N_NODES * 4, stream);
    k_atom_encode<<<N_NODES / 4, 256, 0, stream>>>(x, atom_emb, h);
    k_convert_w<<<512, 256, 0, stream>>>(lin1_w, lin2_w, wtb);
    k_count<<<2048, 256, 0, stream>>>(edst, cursor);
    k_scan1<<<SCAN_BLOCKS, 1024, 0, stream>>>(cursor, local, blocksum);
    k_scan2<<<1, 64, 0, stream>>>(blocksum, row_ptr);
    k_scan3<<<SCAN_BLOCKS, 1024, 0, stream>>>(local, blocksum, row_ptr, cursor);
    k_scatter<<<2048, 256, 0, stream>>>(esrc, edst, edge_attr, cursor, perm);

    int mlp_grid = (N_NODES + MROWS - 1) / MROWS;   // 782
    for (int i = 0; i < NLAYER; ++i) {
        k_aggregate<<<N_NODES / 4, 256, 0, stream>>>(h, row_ptr, perm, bond_emb, zb);
        k_mlp_mfma<<<mlp_grid, 256, 0, stream>>>((const unsigned short*)zb,
                                                 wtb + (size_t)(i * 2 + 0) * HID * HID,
                                                 lin1_b + (size_t)i * HID,
                                                 wtb + (size_t)(i * 2 + 1) * HID * HID,
                                                 lin2_b + (size_t)i * HID,
                                                 bn_gamma + (size_t)i * HID,
                                                 bn_beta + (size_t)i * HID,
                                                 bn_mean + (size_t)i * HID,
                                                 bn_var + (size_t)i * HID, h);
    }
    k_pool_mlp<<<N_GRAPHS, HID, 0, stream>>>(batch, h, mlp_w, mlp_b, out);
}